// Round 7
// baseline (472.750 us; speedup 1.0000x reference)
//
#include <hip/hip_runtime.h>

// Problem: T=2048, B=16, N=2048, binary fp32 spikes, duration=100.
// out[t,b,n] = 1 if any spike in window [t-duration+1, t], else 0.
//
// Bitmask pipeline (R6) rebuilt: R6's three phases summed ~186us, far off
// the ~86us stream floor. Defects: binarize used 2x shfl_xor (DS-pipe,
// loop-carried) + 3/4-masked stores; expand decoded via lane-variable
// funnel from shared words. This revision:
//   1) binarize: lane loads float4 (1KB/wave contiguous), 4x __ballot
//      -> 4 x u64 per 256-col segment, lane0 stores 32B. No DS ops.
//   2) window_or: unchanged from R6 (verified; elementwise over t, so
//      it is oblivious to the ballot bit layout).
//   3) expand: wave reads 32B uniform (L1 same-line broadcast), lane
//      extracts its bit from each u64 -> float4 NT store, 1KB/wave.
// Bit layout contract (binarize <-> expand): segment s covers cols
// [256s, 256s+255]; ballot j holds bit i = (x[s*256 + 4i + j] != 0).

#define T_TOTAL 2048
#define B_DIM   16
#define N_DIM   2048
#define M_COLS  (B_DIM * N_DIM)        // 32768 floats per t-row
#define MW      (M_COLS / 32)          // 1024 u32 words per t-row
#define NSEG    ((long long)T_TOTAL * (M_COLS / 256))   // 262144 wave-segments
#define BM_WORDS ((long long)T_TOTAL * MW)
#define BM_BYTES (BM_WORDS * 4)        // 8 MiB

typedef float v4f __attribute__((ext_vector_type(4)));
typedef unsigned long long u64;

// ---------------- Phase 1: binarize via ballot ----------------
__global__ __launch_bounds__(256) void binarize_kernel(
    const float* __restrict__ x, u64* __restrict__ bm64)
{
    const int lane = threadIdx.x & 63;
    long long w = (long long)((blockIdx.x * blockDim.x + threadIdx.x) >> 6);
    const long long wstep = (gridDim.x * blockDim.x) >> 6;
    for (long long s = w; s < NSEG; s += wstep) {
        v4f v = *((const v4f*)(x + s * 256) + lane);
        u64 b0 = __ballot(v.x != 0.0f);
        u64 b1 = __ballot(v.y != 0.0f);
        u64 b2 = __ballot(v.z != 0.0f);
        u64 b3 = __ballot(v.w != 0.0f);
        if (lane == 0) {
            u64* p = bm64 + s * 4;
            p[0] = b0; p[1] = b1; p[2] = b2; p[3] = b3;
        }
    }
}

// ---------------- Phase 2: sliding-window OR along t (unchanged R6) ----------------
// Elementwise over t per u32 word-column -> independent of bit layout.
#define TCHUNK 128
#define HALO   104
#define ROWS   (TCHUNK + HALO)   // 232
#define WTILE  32

__global__ __launch_bounds__(256) void window_or_kernel(
    const unsigned* __restrict__ bm, unsigned* __restrict__ obm,
    const int* __restrict__ dur_p)
{
    __shared__ unsigned A[ROWS][WTILE];
    __shared__ unsigned Bf[ROWS][WTILE];
    const int w0  = blockIdx.x * WTILE;
    const int t0  = blockIdx.y * TCHUNK;
    const int dur = dur_p[0];

    for (int idx = threadIdx.x; idx < ROWS * WTILE; idx += 256) {
        const int lr = idx / WTILE, w = idx % WTILE;
        const int tg = t0 - HALO + lr;
        A[lr][w] = (tg >= 0) ? bm[(long long)tg * MW + w0 + w] : 0u;
    }
    __syncthreads();

#define LEVEL(SRC, DST, D)                                            \
    for (int idx = threadIdx.x; idx < ROWS * WTILE; idx += 256) {     \
        const int lr = idx / WTILE, w = idx % WTILE;                  \
        unsigned v = SRC[lr][w];                                      \
        if (lr >= D) v |= SRC[lr - D][w];                             \
        DST[lr][w] = v;                                               \
    }                                                                 \
    __syncthreads();

    LEVEL(A, Bf, 1)    // O2
    LEVEL(Bf, A, 2)    // O4
    LEVEL(A, Bf, 4)    // O8
    LEVEL(Bf, A, 8)    // O16
    LEVEL(A, Bf, 16)   // O32 (in Bf)
    LEVEL(Bf, A, 32)   // O64 (in A)
#undef LEVEL

    for (int idx = threadIdx.x; idx < TCHUNK * WTILE; idx += 256) {
        const int r = idx / WTILE, w = idx % WTILE;
        const int lr = HALO + r;
        unsigned v;
        if (dur >= 65) {
            v = A[lr][w] | A[lr - (dur - 64)][w];
        } else if (dur >= 33) {
            v = Bf[lr][w] | Bf[lr - (dur - 32)][w];
        } else {
            v = 0u;
            const int tg = t0 + r;
            for (int k = 0; k < dur && k <= tg; ++k)
                v |= bm[(long long)(tg - k) * MW + w0 + w];
        }
        obm[(long long)(t0 + r) * MW + w0 + w] = v;
    }
}

// ---------------- Phase 3: expand via uniform 32B read + bit extract ----------------
__global__ __launch_bounds__(256) void expand_kernel(
    const u64* __restrict__ obm64, float* __restrict__ out)
{
    const int lane = threadIdx.x & 63;
    long long w = (long long)((blockIdx.x * blockDim.x + threadIdx.x) >> 6);
    const long long wstep = (gridDim.x * blockDim.x) >> 6;
    for (long long s = w; s < NSEG; s += wstep) {
        const u64* p = obm64 + s * 4;
        u64 b0 = p[0], b1 = p[1], b2 = p[2], b3 = p[3];
        v4f o;
        o.x = ((b0 >> lane) & 1ull) ? 1.0f : 0.0f;
        o.y = ((b1 >> lane) & 1ull) ? 1.0f : 0.0f;
        o.z = ((b2 >> lane) & 1ull) ? 1.0f : 0.0f;
        o.w = ((b3 >> lane) & 1ull) ? 1.0f : 0.0f;
        __builtin_nontemporal_store(o, (v4f*)(out + s * 256) + lane);
    }
}

// ---------------- Fallback: verified single-pass scan ----------------
#define FCHUNK 256
__global__ __launch_bounds__(256) void psp_scan_fallback(
    const float* __restrict__ x, const int* __restrict__ dur_p,
    float* __restrict__ out)
{
    const int col = blockIdx.x * blockDim.x + threadIdx.x;
    const int t0  = blockIdx.y * FCHUNK;
    const int duration = dur_p[0];
    int last = t0 - duration;
    int tstart = t0 - duration + 1;
    if (tstart < 0) tstart = 0;
    const float* xc = x + col;
    float* oc = out + col;
    for (int t = tstart; t < t0; ++t)
        if (xc[t * M_COLS] != 0.0f) last = t;
    #pragma unroll 4
    for (int t = t0; t < t0 + FCHUNK; ++t) {
        if (xc[t * M_COLS] != 0.0f) last = t;
        oc[t * M_COLS] = (t - last < duration) ? 1.0f : 0.0f;
    }
}

extern "C" void kernel_launch(void* const* d_in, const int* in_sizes, int n_in,
                              void* d_out, int out_size, void* d_ws, size_t ws_size,
                              hipStream_t stream) {
    const float* x     = (const float*)d_in[0];
    const int*   dur_p = (const int*)d_in[1];
    float*       out   = (float*)d_out;

    if (d_ws != nullptr && ws_size >= (size_t)(2 * BM_BYTES)) {
        u64* bm64  = (u64*)d_ws;
        u64* obm64 = bm64 + BM_WORDS / 2;
        binarize_kernel<<<dim3(2048), dim3(256), 0, stream>>>(x, bm64);
        window_or_kernel<<<dim3(MW / WTILE, T_TOTAL / TCHUNK), dim3(256), 0, stream>>>(
            (const unsigned*)bm64, (unsigned*)obm64, dur_p);
        expand_kernel<<<dim3(2048), dim3(256), 0, stream>>>(obm64, out);
    } else {
        dim3 grid(M_COLS / 256, T_TOTAL / FCHUNK);
        psp_scan_fallback<<<grid, dim3(256), 0, stream>>>(x, dur_p, out);
    }
}